// Round 2
// baseline (79.398 us; speedup 1.0000x reference)
//
#include <hip/hip_runtime.h>

#define N_RAY 131072
#define NS 128
#define BIG_DELTA 1e10f
#define EPS 1e-10f

// 32 lanes per ray, 4 consecutive samples per lane (all loads are float4 =
// 16 B/lane). Two rays per wave64 via width-32 segmented shuffles.
// Exclusive cumprod: width-32 Hillis-Steele scan of per-lane 4-products.
__global__ __launch_bounds__(256) void volrender_kernel(
    const float4* __restrict__ rgb4,    // N_RAY * 96 float4
    const float4* __restrict__ sigma4,  // N_RAY * 32 float4
    const float4* __restrict__ z4,      // N_RAY * 32 float4
    const int* __restrict__ wb_flag,
    float* __restrict__ out)
{
    const int tid = blockIdx.x * blockDim.x + threadIdx.x;
    const int ray = tid >> 5;           // 32 lanes per ray
    const int l   = threadIdx.x & 31;   // lane within ray segment
    if (ray >= N_RAY) return;

    const float4 z = z4[(size_t)ray * 32 + l];
    const float4 s = sigma4[(size_t)ray * 32 + l];

    // deltas (sample 4l..4l+3)
    float z_next = __shfl_down(z.x, 1, 32);   // z[4l+4] (l < 31)
    float d0 = z.y - z.x;
    float d1 = z.z - z.y;
    float d2 = z.w - z.z;
    float d3 = (l == 31) ? BIG_DELTA : (z_next - z.w);

    // alpha = 1 - exp(-delta * relu(sigma))
    float a0 = 1.0f - __expf(-d0 * fmaxf(s.x, 0.0f));
    float a1 = 1.0f - __expf(-d1 * fmaxf(s.y, 0.0f));
    float a2 = 1.0f - __expf(-d2 * fmaxf(s.z, 0.0f));
    float a3 = 1.0f - __expf(-d3 * fmaxf(s.w, 0.0f));

    float t0 = 1.0f - a0 + EPS;
    float t1 = 1.0f - a1 + EPS;
    float t2 = 1.0f - a2 + EPS;
    float t3 = 1.0f - a3 + EPS;

    // inclusive scan of per-lane 4-products across the 32-lane segment
    float p = (t0 * t1) * (t2 * t3);
    #pragma unroll
    for (int d = 1; d < 32; d <<= 1) {
        float q = __shfl_up(p, d, 32);
        if (l >= d) p *= q;
    }
    // exclusive prefix for this lane's first sample
    float e = __shfl_up(p, 1, 32);
    if (l == 0) e = 1.0f;

    // weights
    float w0 = a0 * e;
    float e1 = e * t0;
    float w1 = a1 * e1;
    float e2 = e1 * t1;
    float w2 = a2 * e2;
    float w3 = a3 * (e2 * t2);

    // weights output: after comp_rgb(3N) + depth(N) + opacity(N)
    float4* wout = reinterpret_cast<float4*>(out + (size_t)N_RAY * 5) + (size_t)ray * 32 + l;
    *wout = make_float4(w0, w1, w2, w3);

    // rgb: 12 contiguous floats per lane = 3 aligned float4s
    const float4* rp = rgb4 + (size_t)ray * 96 + 3 * l;
    float4 c0 = rp[0];
    float4 c1 = rp[1];
    float4 c2 = rp[2];

    // sample k channels: s0=(c0.x,c0.y,c0.z) s1=(c0.w,c1.x,c1.y)
    //                    s2=(c1.z,c1.w,c2.x) s3=(c2.y,c2.z,c2.w)
    float r   = w0 * c0.x + w1 * c0.w + w2 * c1.z + w3 * c2.y;
    float g   = w0 * c0.y + w1 * c1.x + w2 * c1.w + w3 * c2.z;
    float b   = w0 * c0.z + w1 * c1.y + w2 * c2.x + w3 * c2.w;
    float dep = w0 * z.x  + w1 * z.y  + w2 * z.z  + w3 * z.w;
    float op  = w0 + w1 + w2 + w3;

    // segmented reduction over 32 lanes
    #pragma unroll
    for (int d = 16; d > 0; d >>= 1) {
        r   += __shfl_down(r,   d, 32);
        g   += __shfl_down(g,   d, 32);
        b   += __shfl_down(b,   d, 32);
        dep += __shfl_down(dep, d, 32);
        op  += __shfl_down(op,  d, 32);
    }

    if (l == 0) {
        const int wb = *wb_flag;
        const float add = wb ? (1.0f - op) : 0.0f;
        out[(size_t)ray * 3 + 0] = r + add;
        out[(size_t)ray * 3 + 1] = g + add;
        out[(size_t)ray * 3 + 2] = b + add;
        out[(size_t)N_RAY * 3 + ray] = dep;
        out[(size_t)N_RAY * 4 + ray] = op;
    }
}

extern "C" void kernel_launch(void* const* d_in, const int* in_sizes, int n_in,
                              void* d_out, int out_size, void* d_ws, size_t ws_size,
                              hipStream_t stream) {
    const float4* rgb    = (const float4*)d_in[0];
    const float4* sigma  = (const float4*)d_in[1];
    const float4* z_vals = (const float4*)d_in[2];
    const int*    wb     = (const int*)d_in[3];
    float* out = (float*)d_out;

    // 8 rays per 256-thread block (32 lanes per ray)
    const int blocks = (N_RAY * 32) / 256;
    volrender_kernel<<<blocks, 256, 0, stream>>>(rgb, sigma, z_vals, wb, out);
}